// Round 2
// baseline (311.252 us; speedup 1.0000x reference)
//
#include <hip/hip_runtime.h>
#include <hip/hip_bf16.h>

// ---------------------------------------------------------------------------
// GraphSAGE (3x SAGEConv mean + linear head), CSR gather formulation.
// R12 = R11 + occupancy pass on the MFMA-path kernels:
//   All three MFMA kernels moved from 64-node blocks (3128 waves total,
//   ~3.05 waves/SIMD chip-wide) to 32-node blocks with 16-row wave tiles
//   (6252 waves, ~6.1 waves/SIMD). Doubles TLP for hiding the L2-latency
//   gather/fragment-load chains; halves per-wave VGPR for A-fragments.
// Deduction from R11 counters: no kernel exceeds 44.6us (all below the
// harness fill dispatches) -> runtime is spread, no single hot kernel.
// R9 lesson kept: do NOT fuse random gather into the GEMM kernel.
// ---------------------------------------------------------------------------

#define SCAN_CHUNK 2048

typedef unsigned short bf16_t;
typedef unsigned int uint32;
typedef __attribute__((ext_vector_type(8))) short bf16x8;   // 8 bf16 = 4 VGPRs
typedef __attribute__((ext_vector_type(4))) float f32x4;

__device__ __forceinline__ bf16_t f2bf(float f) {
    uint32 u = __float_as_uint(f);
    u += 0x7fff + ((u >> 16) & 1);           // round-to-nearest-even
    return (bf16_t)(u >> 16);
}
__device__ __forceinline__ float bf2f(bf16_t b) {
    return __uint_as_float((uint32)b << 16);
}
__device__ __forceinline__ void acc8(float* acc, uint4 v) {
    acc[0] += bf2f((bf16_t)(v.x & 0xffff)); acc[1] += bf2f((bf16_t)(v.x >> 16));
    acc[2] += bf2f((bf16_t)(v.y & 0xffff)); acc[3] += bf2f((bf16_t)(v.y >> 16));
    acc[4] += bf2f((bf16_t)(v.z & 0xffff)); acc[5] += bf2f((bf16_t)(v.z >> 16));
    acc[6] += bf2f((bf16_t)(v.w & 0xffff)); acc[7] += bf2f((bf16_t)(v.w >> 16));
}

// ---- setup: zero deg + convert all three weight matrices to bf16 ----------
__global__ __launch_bounds__(256) void prep_kernel(
    int* __restrict__ deg, int N,
    const float* __restrict__ Wl1, const float* __restrict__ Wr1, bf16_t* __restrict__ w1,
    const float* __restrict__ Wl2, const float* __restrict__ Wr2, bf16_t* __restrict__ w2,
    const float* __restrict__ Wl3, const float* __restrict__ Wr3, bf16_t* __restrict__ w3) {
    const int nZero = (N + 255) >> 8;
    const int b = blockIdx.x;
    const int t = threadIdx.x;
    if (b < nZero) {
        int i = b * 256 + t;
        if (i < N) deg[i] = 0;
    } else if (b < nZero + 16) {
        int idx = (b - nZero) * 256 + t;         // 0..4095
        int o = idx >> 5, k = idx & 31;
        float v = (k < 16) ? Wl1[o * 16 + k] : Wr1[o * 16 + k - 16];
        w1[idx] = f2bf(v);
    } else if (b < nZero + 144) {
        int idx = (b - nZero - 16) * 256 + t;    // 0..32767
        int o = idx >> 8, k = idx & 255;
        float v = (k < 128) ? Wl2[o * 128 + k] : Wr2[o * 128 + k - 128];
        w2[idx] = f2bf(v);
    } else {
        int idx = (b - nZero - 144) * 256 + t;
        int o = idx >> 8, k = idx & 255;
        float v = (k < 128) ? Wl3[o * 128 + k] : Wr3[o * 128 + k - 128];
        w3[idx] = f2bf(v);
    }
}

__global__ void count_deg_kernel(const int* __restrict__ dst, int* __restrict__ deg, int E) {
    int e = blockIdx.x * 256 + threadIdx.x;
    if (e < E) atomicAdd(&deg[dst[e]], 1);
}

__global__ __launch_bounds__(256) void scan_partial_kernel(
    const int* __restrict__ deg, int* __restrict__ blocksum, int N) {
    __shared__ int s[256];
    const int t = threadIdx.x;
    const int base = blockIdx.x * SCAN_CHUNK + t * 8;
    int sum = 0;
    #pragma unroll
    for (int j = 0; j < 8; ++j) {
        int i = base + j;
        if (i < N) sum += deg[i];
    }
    s[t] = sum;
    __syncthreads();
    #pragma unroll
    for (int off = 128; off > 0; off >>= 1) {
        if (t < off) s[t] += s[t + off];
        __syncthreads();
    }
    if (t == 0) blocksum[blockIdx.x] = s[0];
}

__global__ __launch_bounds__(256) void scan_final_kernel(
    const int* __restrict__ deg, const int* __restrict__ blocksum,
    int* __restrict__ rowptr, int* __restrict__ cursor,
    float* __restrict__ inv, int N) {
    __shared__ int s[256];
    __shared__ int blockoff_s;
    const int t = threadIdx.x;
    if (t == 0) {
        int off = 0;
        for (int b = 0; b < (int)blockIdx.x; ++b) off += blocksum[b];
        blockoff_s = off;
    }
    const int base = blockIdx.x * SCAN_CHUNK + t * 8;
    int v[8];
    int sum = 0;
    #pragma unroll
    for (int j = 0; j < 8; ++j) {
        int i = base + j;
        v[j] = (i < N) ? deg[i] : 0;
        sum += v[j];
    }
    s[t] = sum;
    __syncthreads();
    for (int off = 1; off < 256; off <<= 1) {
        int val = (t >= off) ? s[t - off] : 0;
        __syncthreads();
        s[t] += val;
        __syncthreads();
    }
    int run = blockoff_s + ((t == 0) ? 0 : s[t - 1]);
    #pragma unroll
    for (int j = 0; j < 8; ++j) {
        int i = base + j;
        if (i < N) {
            rowptr[i] = run;
            cursor[i] = run;
            inv[i] = 1.0f / (float)max(v[j], 1);
            run += v[j];
        }
    }
    if ((int)blockIdx.x == (int)gridDim.x - 1 && t == 255) rowptr[N] = run;
}

__global__ void fill_csr_kernel(const int* __restrict__ src, const int* __restrict__ dst,
                                int* __restrict__ cursor, int* __restrict__ col, int E) {
    int e = blockIdx.x * 256 + threadIdx.x;
    if (e >= E) return;
    int pos = atomicAdd(&cursor[dst[e]], 1);
    col[pos] = src[e];
}

// ---- layer 1 fused: gather x-mean + MFMA (K=32) --------------------------
// R12: 32-node blocks, one 16-row tile per wave (wave>>1 = row half,
// wave&1 = col half). 6252 waves (~6.1/SIMD) vs 3128 before. Gather
// structure from R11 kept: all 4 q-lanes gather (qh = row half, qe = edge
// parity), shfl_xor(32) combine; self-row overwrite on q>=2.
__global__ __launch_bounds__(256) void layer16_fused_kernel(
    const float* __restrict__ x, const int* __restrict__ rowptr,
    const int* __restrict__ col, const float* __restrict__ inv,
    const bf16_t* __restrict__ wbf1, const float* __restrict__ bias,
    bf16_t* __restrict__ hout, int n) {
    const int t = threadIdx.x;
    const int lane = t & 63;
    const int wave = t >> 6;
    const int r = lane & 15;
    const int q = lane >> 4;
    const int qh = q & 1;
    const int qe = q >> 1;
    const int m0 = blockIdx.x * 32 + (wave >> 1) * 16;
    const int nb = (wave & 1) * 64;

    bf16x8 aF;
    {
        int node = m0 + r;
        if (node >= n) node = n - 1;
        float acc[8];
        #pragma unroll
        for (int j = 0; j < 8; ++j) acc[j] = 0.f;
        const int lo = rowptr[node], hi = rowptr[node + 1];
        int e = lo + qe;
        for (; e + 2 < hi; e += 4) {         // two edges per iter per stream
            int s0 = col[e], s1 = col[e + 2];
            float4 u0 = *(const float4*)&x[s0 * 16 + qh * 8];
            float4 u1 = *(const float4*)&x[s0 * 16 + qh * 8 + 4];
            float4 u2 = *(const float4*)&x[s1 * 16 + qh * 8];
            float4 u3 = *(const float4*)&x[s1 * 16 + qh * 8 + 4];
            acc[0] += u0.x + u2.x; acc[1] += u0.y + u2.y;
            acc[2] += u0.z + u2.z; acc[3] += u0.w + u2.w;
            acc[4] += u1.x + u3.x; acc[5] += u1.y + u3.y;
            acc[6] += u1.z + u3.z; acc[7] += u1.w + u3.w;
        }
        for (; e < hi; e += 2) {
            int s0 = col[e];
            float4 u0 = *(const float4*)&x[s0 * 16 + qh * 8];
            float4 u1 = *(const float4*)&x[s0 * 16 + qh * 8 + 4];
            acc[0] += u0.x; acc[1] += u0.y; acc[2] += u0.z; acc[3] += u0.w;
            acc[4] += u1.x; acc[5] += u1.y; acc[6] += u1.z; acc[7] += u1.w;
        }
        // combine the two edge-parity streams (lane ^ 32 flips qe, keeps r,qh)
        #pragma unroll
        for (int j = 0; j < 8; ++j) acc[j] += __shfl_xor(acc[j], 32);
        if (q < 2) {
            float iv = inv[node];
            #pragma unroll
            for (int j = 0; j < 8; ++j) acc[j] *= iv;
        } else {
            // self-row half qh (K slots 16..31 of the fused K=32 fragment)
            float4 u0 = *(const float4*)&x[node * 16 + qh * 8];
            float4 u1 = *(const float4*)&x[node * 16 + qh * 8 + 4];
            acc[0] = u0.x; acc[1] = u0.y; acc[2] = u0.z; acc[3] = u0.w;
            acc[4] = u1.x; acc[5] = u1.y; acc[6] = u1.z; acc[7] = u1.w;
        }
        #pragma unroll
        for (int j = 0; j < 8; ++j) aF[j] = (short)f2bf(acc[j]);
    }

    #pragma unroll
    for (int nt = 0; nt < 4; ++nt) {
        const int cidx = nb + nt * 16 + r;
        bf16x8 bF = *(const bf16x8*)(wbf1 + (size_t)cidx * 32 + q * 8);
        f32x4 acc0 = {0.f, 0.f, 0.f, 0.f};
        acc0 = __builtin_amdgcn_mfma_f32_16x16x32_bf16(aF, bF, acc0, 0, 0, 0);
        float bo = bias[cidx];
        #pragma unroll
        for (int reg = 0; reg < 4; ++reg) {
            int row0 = m0 + q * 4 + reg;
            if (row0 < n)
                hout[(size_t)row0 * 128 + cidx] = f2bf(fmaxf(acc0[reg] + bo, 0.0f));
        }
    }
}

// ---- high-occupancy coalesced mean aggregate ------------------------------
// 32 lanes/node = 2 edge-parity streams x 16 dim-lanes (16B each).
// Streams combined via one shfl_xor(16) pass; sub==0 half stores.
// Already at 8 waves/SIMD cap (25k waves) -> unchanged this round.
__global__ __launch_bounds__(256) void aggregate128_kernel(
    const bf16_t* __restrict__ h, const int* __restrict__ rowptr,
    const int* __restrict__ col, const float* __restrict__ inv,
    bf16_t* __restrict__ aggb, int N) {
    const int t = threadIdx.x;
    const int node = blockIdx.x * 8 + (t >> 5);
    const int sub = (t >> 4) & 1;            // edge-parity stream
    const int li = t & 15;                   // 8-bf16 (16B) column slot
    if (node >= N) return;
    const int lo = rowptr[node], hi = rowptr[node + 1];
    float acc[8];
    #pragma unroll
    for (int j = 0; j < 8; ++j) acc[j] = 0.0f;
    int e = lo + sub;
    for (; e + 6 < hi; e += 8) {             // 4 edges per iter per stream
        int s0 = col[e], s1 = col[e + 2], s2 = col[e + 4], s3 = col[e + 6];
        uint4 v0 = *(const uint4*)&h[(size_t)s0 * 128 + li * 8];
        uint4 v1 = *(const uint4*)&h[(size_t)s1 * 128 + li * 8];
        uint4 v2 = *(const uint4*)&h[(size_t)s2 * 128 + li * 8];
        uint4 v3 = *(const uint4*)&h[(size_t)s3 * 128 + li * 8];
        acc8(acc, v0);
        acc8(acc, v1);
        acc8(acc, v2);
        acc8(acc, v3);
    }
    for (; e < hi; e += 2) {
        uint4 v0 = *(const uint4*)&h[(size_t)col[e] * 128 + li * 8];
        acc8(acc, v0);
    }
    // combine streams: lane ^ 16 flips sub, keeps li and node
    #pragma unroll
    for (int j = 0; j < 8; ++j) acc[j] += __shfl_xor(acc[j], 16);
    if (sub == 0) {
        const float iv = inv[node];
        uint4 pk;
        pk.x = (uint32)f2bf(acc[0] * iv) | ((uint32)f2bf(acc[1] * iv) << 16);
        pk.y = (uint32)f2bf(acc[2] * iv) | ((uint32)f2bf(acc[3] * iv) << 16);
        pk.z = (uint32)f2bf(acc[4] * iv) | ((uint32)f2bf(acc[5] * iv) << 16);
        pk.w = (uint32)f2bf(acc[6] * iv) | ((uint32)f2bf(acc[7] * iv) << 16);
        *(uint4*)&aggb[(size_t)node * 128 + li * 8] = pk;
    }
}

// ---- layer 2: MFMA bf16 GEMM, K=256, fragments straight from global ------
// R12: 32-node blocks, 16-row tile per wave. aF halves to 8 frags (32 VGPR).
__global__ __launch_bounds__(256) void layer128_mfma_kernel(
    const bf16_t* __restrict__ aggb, const bf16_t* __restrict__ hin,
    const bf16_t* __restrict__ wbf, const float* __restrict__ bias,
    bf16_t* __restrict__ hout, int n) {
    const int t = threadIdx.x;
    const int lane = t & 63;
    const int wave = t >> 6;
    const int r = lane & 15;
    const int q = lane >> 4;
    const int m0 = blockIdx.x * 32 + (wave >> 1) * 16;
    const int nb = (wave & 1) * 64;

    bf16x8 aF[8];
    {
        int node = m0 + r;
        if (node >= n) node = n - 1;
        const bf16_t* arow = aggb + (size_t)node * 128;
        const bf16_t* hrow = hin + (size_t)node * 128;
        #pragma unroll
        for (int ks = 0; ks < 4; ++ks)
            aF[ks] = *(const bf16x8*)(arow + ks * 32 + q * 8);
        #pragma unroll
        for (int ks = 0; ks < 4; ++ks)
            aF[4 + ks] = *(const bf16x8*)(hrow + ks * 32 + q * 8);
    }

    #pragma unroll
    for (int nt = 0; nt < 4; ++nt) {
        const int cidx = nb + nt * 16 + r;
        const bf16_t* wrow = wbf + (size_t)cidx * 256;
        f32x4 acc0 = {0.f, 0.f, 0.f, 0.f};
        #pragma unroll
        for (int ks = 0; ks < 8; ++ks) {
            bf16x8 bF = *(const bf16x8*)(wrow + ks * 32 + q * 8);
            acc0 = __builtin_amdgcn_mfma_f32_16x16x32_bf16(aF[ks], bF, acc0, 0, 0, 0);
        }
        float bo = bias[cidx];
        #pragma unroll
        for (int reg = 0; reg < 4; ++reg) {
            int row0 = m0 + q * 4 + reg;
            if (row0 < n)
                hout[(size_t)row0 * 128 + cidx] = f2bf(fmaxf(acc0[reg] + bo, 0.0f));
        }
    }
}

// ---- layer 3 + head fused via LDS tile -----------------------------------
// R12: 32-node blocks; head GEMV uses threads t<128 (4 outs x 32 nodes).
__global__ __launch_bounds__(256) void layer128_head_mfma_kernel(
    const bf16_t* __restrict__ aggb, const bf16_t* __restrict__ hin,
    const bf16_t* __restrict__ wbf, const float* __restrict__ bias,
    const float* __restrict__ Wh, const float* __restrict__ bh,
    float* __restrict__ out, int n) {
    __shared__ bf16_t hs[32][132];

    const int t = threadIdx.x;
    const int lane = t & 63;
    const int wave = t >> 6;
    const int r = lane & 15;
    const int q = lane >> 4;
    const int n0 = blockIdx.x * 32;
    const int m0 = n0 + (wave >> 1) * 16;
    const int nb = (wave & 1) * 64;

    bf16x8 aF[8];
    {
        int node = m0 + r;
        if (node >= n) node = n - 1;
        const bf16_t* arow = aggb + (size_t)node * 128;
        const bf16_t* hrow = hin + (size_t)node * 128;
        #pragma unroll
        for (int ks = 0; ks < 4; ++ks)
            aF[ks] = *(const bf16x8*)(arow + ks * 32 + q * 8);
        #pragma unroll
        for (int ks = 0; ks < 4; ++ks)
            aF[4 + ks] = *(const bf16x8*)(hrow + ks * 32 + q * 8);
    }

    const int mloc = (wave >> 1) * 16;
    #pragma unroll
    for (int nt = 0; nt < 4; ++nt) {
        const int cidx = nb + nt * 16 + r;
        const bf16_t* wrow = wbf + (size_t)cidx * 256;
        f32x4 acc0 = {0.f, 0.f, 0.f, 0.f};
        #pragma unroll
        for (int ks = 0; ks < 8; ++ks) {
            bf16x8 bF = *(const bf16x8*)(wrow + ks * 32 + q * 8);
            acc0 = __builtin_amdgcn_mfma_f32_16x16x32_bf16(aF[ks], bF, acc0, 0, 0, 0);
        }
        float bo = bias[cidx];
        #pragma unroll
        for (int reg = 0; reg < 4; ++reg) {
            hs[mloc + q * 4 + reg][cidx] = f2bf(fmaxf(acc0[reg] + bo, 0.0f));
        }
    }
    __syncthreads();

    const int nl = t >> 2;                   // 0..63, valid 0..31
    const int o  = t & 3;
    const int node = n0 + nl;
    if (nl >= 32 || node >= n) return;
    const float* wr = Wh + o * 128;
    float acc = bh[o];
    #pragma unroll
    for (int kb = 0; kb < 16; ++kb) {
        bf16x8 hv = *(const bf16x8*)&hs[nl][kb * 8];
        float4 w0 = *(const float4*)&wr[kb * 8];
        float4 w1 = *(const float4*)&wr[kb * 8 + 4];
        acc = fmaf(bf2f((bf16_t)hv[0]), w0.x, acc);
        acc = fmaf(bf2f((bf16_t)hv[1]), w0.y, acc);
        acc = fmaf(bf2f((bf16_t)hv[2]), w0.z, acc);
        acc = fmaf(bf2f((bf16_t)hv[3]), w0.w, acc);
        acc = fmaf(bf2f((bf16_t)hv[4]), w1.x, acc);
        acc = fmaf(bf2f((bf16_t)hv[5]), w1.y, acc);
        acc = fmaf(bf2f((bf16_t)hv[6]), w1.z, acc);
        acc = fmaf(bf2f((bf16_t)hv[7]), w1.w, acc);
    }
    out[(size_t)node * 4 + o] = acc;
}

extern "C" void kernel_launch(void* const* d_in, const int* in_sizes, int n_in,
                              void* d_out, int out_size, void* d_ws, size_t ws_size,
                              hipStream_t stream) {
    const float* x   = (const float*)d_in[0];
    const int*   ei  = (const int*)d_in[1];
    const float* Wl1 = (const float*)d_in[2];
    const float* Wr1 = (const float*)d_in[3];
    const float* b1  = (const float*)d_in[4];
    const float* Wl2 = (const float*)d_in[5];
    const float* Wr2 = (const float*)d_in[6];
    const float* b2  = (const float*)d_in[7];
    const float* Wl3 = (const float*)d_in[8];
    const float* Wr3 = (const float*)d_in[9];
    const float* b3  = (const float*)d_in[10];
    const float* Wh  = (const float*)d_in[11];
    const float* bh  = (const float*)d_in[12];
    float* out = (float*)d_out;

    const int N = in_sizes[0] / 16;
    const int E = in_sizes[1] / 2;
    const int* src = ei;
    const int* dst = ei + E;

    const int nScanBlocks = (N + SCAN_CHUNK - 1) / SCAN_CHUNK;
    const int nZero = (N + 255) >> 8;

    int* deg       = (int*)d_ws;                       // N
    int* rowptr    = deg + N;                          // N+1 (pad 8)
    int* cursor    = rowptr + (N + 8);                 // N
    int* blocksum  = cursor + N;                       // pad 64
    int* col       = blocksum + 64;                    // E
    float* inv     = (float*)(col + E);                // N
    bf16_t* aggb   = (bf16_t*)(inv + N);               // N*128 bf16
    bf16_t* hA     = aggb + (size_t)N * 128;           // N*128 bf16
    bf16_t* hB     = hA + (size_t)N * 128;             // N*128 bf16
    bf16_t* wbf1   = hB + (size_t)N * 128;             // 128*32 bf16
    bf16_t* wbf2   = wbf1 + 128 * 32;                  // 128*256 bf16
    bf16_t* wbf3   = wbf2 + 128 * 256;                 // 128*256 bf16

    const int B = 256;
    auto blocks = [](long total, int b) { return (int)((total + b - 1) / b); };

    // ---- setup + CSR build (5 dispatches) ----
    prep_kernel<<<nZero + 272, B, 0, stream>>>(deg, N, Wl1, Wr1, wbf1,
                                               Wl2, Wr2, wbf2, Wl3, Wr3, wbf3);
    count_deg_kernel<<<blocks(E, B), B, 0, stream>>>(dst, deg, E);
    scan_partial_kernel<<<nScanBlocks, B, 0, stream>>>(deg, blocksum, N);
    scan_final_kernel<<<nScanBlocks, B, 0, stream>>>(deg, blocksum, rowptr, cursor, inv, N);
    fill_csr_kernel<<<blocks(E, B), B, 0, stream>>>(src, dst, cursor, col, E);

    // ---- layer 1: fused x-gather + MFMA (K=32) ----
    layer16_fused_kernel<<<blocks(N, 32), B, 0, stream>>>(
        x, rowptr, col, inv, wbf1, b1, hA, N);

    // ---- layer 2: aggregate + MFMA GEMM ----
    aggregate128_kernel<<<blocks(N, 8), B, 0, stream>>>(hA, rowptr, col, inv, aggb, N);
    layer128_mfma_kernel<<<blocks(N, 32), B, 0, stream>>>(aggb, hA, wbf2, b2, hB, N);

    // ---- layer 3 + head fused ----
    aggregate128_kernel<<<blocks(N, 8), B, 0, stream>>>(hB, rowptr, col, inv, aggb, N);
    layer128_head_mfma_kernel<<<blocks(N, 32), B, 0, stream>>>(
        aggb, hB, wbf3, b3, Wh, bh, out, N);
}

// Round 4
// 280.779 us; speedup vs baseline: 1.1085x; 1.1085x over previous
//
#include <hip/hip_runtime.h>
#include <hip/hip_bf16.h>

// ---------------------------------------------------------------------------
// GraphSAGE (3x SAGEConv mean + linear head), CSR gather formulation.
// R14 = R13 resubmitted verbatim (R13 never ran: GPU acquisition timeout).
// R13: LDS-staged weight GEMMs + split head.
// R12 counter evidence: layer128_head_mfma 46.5us @ MfmaUtil 2.4%, VALU 5%,
// 303 GB/s, VGPR=36 -> per-wave ~18k cycles = serial global bF loads
// (no regs to hoist; each MFMA waits ~200cy L2). Fix:
//   - layer128_mfma: block = 128 rows x 64 cols, weight half (64x256)
//     staged in 32KB LDS in FRAGMENT-MAJOR order (chunk = (nt*8+ks)*64 +
//     r*4+q -> each wave ds_read_b128 is a lane-bijective 1024B read,
//     conflict-free). 2 M-frags/wave restores x2 bF reuse.
//   - head split into a 4-lane-per-node GEMV kernel (h3 via hA reuse);
//     layer3 uses the same staged GEMM kernel.
// R9 lesson kept: do NOT fuse random gather into the GEMM kernel.
// ---------------------------------------------------------------------------

#define SCAN_CHUNK 2048

typedef unsigned short bf16_t;
typedef unsigned int uint32;
typedef __attribute__((ext_vector_type(8))) short bf16x8;   // 8 bf16 = 4 VGPRs
typedef __attribute__((ext_vector_type(4))) float f32x4;

__device__ __forceinline__ bf16_t f2bf(float f) {
    uint32 u = __float_as_uint(f);
    u += 0x7fff + ((u >> 16) & 1);           // round-to-nearest-even
    return (bf16_t)(u >> 16);
}
__device__ __forceinline__ float bf2f(bf16_t b) {
    return __uint_as_float((uint32)b << 16);
}
__device__ __forceinline__ void acc8(float* acc, uint4 v) {
    acc[0] += bf2f((bf16_t)(v.x & 0xffff)); acc[1] += bf2f((bf16_t)(v.x >> 16));
    acc[2] += bf2f((bf16_t)(v.y & 0xffff)); acc[3] += bf2f((bf16_t)(v.y >> 16));
    acc[4] += bf2f((bf16_t)(v.z & 0xffff)); acc[5] += bf2f((bf16_t)(v.z >> 16));
    acc[6] += bf2f((bf16_t)(v.w & 0xffff)); acc[7] += bf2f((bf16_t)(v.w >> 16));
}

// ---- setup: zero deg + convert all three weight matrices to bf16 ----------
__global__ __launch_bounds__(256) void prep_kernel(
    int* __restrict__ deg, int N,
    const float* __restrict__ Wl1, const float* __restrict__ Wr1, bf16_t* __restrict__ w1,
    const float* __restrict__ Wl2, const float* __restrict__ Wr2, bf16_t* __restrict__ w2,
    const float* __restrict__ Wl3, const float* __restrict__ Wr3, bf16_t* __restrict__ w3) {
    const int nZero = (N + 255) >> 8;
    const int b = blockIdx.x;
    const int t = threadIdx.x;
    if (b < nZero) {
        int i = b * 256 + t;
        if (i < N) deg[i] = 0;
    } else if (b < nZero + 16) {
        int idx = (b - nZero) * 256 + t;         // 0..4095
        int o = idx >> 5, k = idx & 31;
        float v = (k < 16) ? Wl1[o * 16 + k] : Wr1[o * 16 + k - 16];
        w1[idx] = f2bf(v);
    } else if (b < nZero + 144) {
        int idx = (b - nZero - 16) * 256 + t;    // 0..32767
        int o = idx >> 8, k = idx & 255;
        float v = (k < 128) ? Wl2[o * 128 + k] : Wr2[o * 128 + k - 128];
        w2[idx] = f2bf(v);
    } else {
        int idx = (b - nZero - 144) * 256 + t;
        int o = idx >> 8, k = idx & 255;
        float v = (k < 128) ? Wl3[o * 128 + k] : Wr3[o * 128 + k - 128];
        w3[idx] = f2bf(v);
    }
}

__global__ void count_deg_kernel(const int* __restrict__ dst, int* __restrict__ deg, int E) {
    int e = blockIdx.x * 256 + threadIdx.x;
    if (e < E) atomicAdd(&deg[dst[e]], 1);
}

__global__ __launch_bounds__(256) void scan_partial_kernel(
    const int* __restrict__ deg, int* __restrict__ blocksum, int N) {
    __shared__ int s[256];
    const int t = threadIdx.x;
    const int base = blockIdx.x * SCAN_CHUNK + t * 8;
    int sum = 0;
    #pragma unroll
    for (int j = 0; j < 8; ++j) {
        int i = base + j;
        if (i < N) sum += deg[i];
    }
    s[t] = sum;
    __syncthreads();
    #pragma unroll
    for (int off = 128; off > 0; off >>= 1) {
        if (t < off) s[t] += s[t + off];
        __syncthreads();
    }
    if (t == 0) blocksum[blockIdx.x] = s[0];
}

__global__ __launch_bounds__(256) void scan_final_kernel(
    const int* __restrict__ deg, const int* __restrict__ blocksum,
    int* __restrict__ rowptr, int* __restrict__ cursor,
    float* __restrict__ inv, int N) {
    __shared__ int s[256];
    __shared__ int blockoff_s;
    const int t = threadIdx.x;
    if (t == 0) {
        int off = 0;
        for (int b = 0; b < (int)blockIdx.x; ++b) off += blocksum[b];
        blockoff_s = off;
    }
    const int base = blockIdx.x * SCAN_CHUNK + t * 8;
    int v[8];
    int sum = 0;
    #pragma unroll
    for (int j = 0; j < 8; ++j) {
        int i = base + j;
        v[j] = (i < N) ? deg[i] : 0;
        sum += v[j];
    }
    s[t] = sum;
    __syncthreads();
    for (int off = 1; off < 256; off <<= 1) {
        int val = (t >= off) ? s[t - off] : 0;
        __syncthreads();
        s[t] += val;
        __syncthreads();
    }
    int run = blockoff_s + ((t == 0) ? 0 : s[t - 1]);
    #pragma unroll
    for (int j = 0; j < 8; ++j) {
        int i = base + j;
        if (i < N) {
            rowptr[i] = run;
            cursor[i] = run;
            inv[i] = 1.0f / (float)max(v[j], 1);
            run += v[j];
        }
    }
    if ((int)blockIdx.x == (int)gridDim.x - 1 && t == 255) rowptr[N] = run;
}

__global__ void fill_csr_kernel(const int* __restrict__ src, const int* __restrict__ dst,
                                int* __restrict__ cursor, int* __restrict__ col, int E) {
    int e = blockIdx.x * 256 + threadIdx.x;
    if (e >= E) return;
    int pos = atomicAdd(&cursor[dst[e]], 1);
    col[pos] = src[e];
}

// ---- layer 1 fused: gather x-mean + MFMA (K=32) --------------------------
// 32-node blocks, one 16-row tile per wave. All 4 q-lanes gather (qh = row
// half, qe = edge parity), shfl_xor(32) combine; self-row overwrite q>=2.
__global__ __launch_bounds__(256) void layer16_fused_kernel(
    const float* __restrict__ x, const int* __restrict__ rowptr,
    const int* __restrict__ col, const float* __restrict__ inv,
    const bf16_t* __restrict__ wbf1, const float* __restrict__ bias,
    bf16_t* __restrict__ hout, int n) {
    const int t = threadIdx.x;
    const int lane = t & 63;
    const int wave = t >> 6;
    const int r = lane & 15;
    const int q = lane >> 4;
    const int qh = q & 1;
    const int qe = q >> 1;
    const int m0 = blockIdx.x * 32 + (wave >> 1) * 16;
    const int nb = (wave & 1) * 64;

    bf16x8 aF;
    {
        int node = m0 + r;
        if (node >= n) node = n - 1;
        float acc[8];
        #pragma unroll
        for (int j = 0; j < 8; ++j) acc[j] = 0.f;
        const int lo = rowptr[node], hi = rowptr[node + 1];
        int e = lo + qe;
        for (; e + 2 < hi; e += 4) {         // two edges per iter per stream
            int s0 = col[e], s1 = col[e + 2];
            float4 u0 = *(const float4*)&x[s0 * 16 + qh * 8];
            float4 u1 = *(const float4*)&x[s0 * 16 + qh * 8 + 4];
            float4 u2 = *(const float4*)&x[s1 * 16 + qh * 8];
            float4 u3 = *(const float4*)&x[s1 * 16 + qh * 8 + 4];
            acc[0] += u0.x + u2.x; acc[1] += u0.y + u2.y;
            acc[2] += u0.z + u2.z; acc[3] += u0.w + u2.w;
            acc[4] += u1.x + u3.x; acc[5] += u1.y + u3.y;
            acc[6] += u1.z + u3.z; acc[7] += u1.w + u3.w;
        }
        for (; e < hi; e += 2) {
            int s0 = col[e];
            float4 u0 = *(const float4*)&x[s0 * 16 + qh * 8];
            float4 u1 = *(const float4*)&x[s0 * 16 + qh * 8 + 4];
            acc[0] += u0.x; acc[1] += u0.y; acc[2] += u0.z; acc[3] += u0.w;
            acc[4] += u1.x; acc[5] += u1.y; acc[6] += u1.z; acc[7] += u1.w;
        }
        // combine the two edge-parity streams (lane ^ 32 flips qe, keeps r,qh)
        #pragma unroll
        for (int j = 0; j < 8; ++j) acc[j] += __shfl_xor(acc[j], 32);
        if (q < 2) {
            float iv = inv[node];
            #pragma unroll
            for (int j = 0; j < 8; ++j) acc[j] *= iv;
        } else {
            // self-row half qh (K slots 16..31 of the fused K=32 fragment)
            float4 u0 = *(const float4*)&x[node * 16 + qh * 8];
            float4 u1 = *(const float4*)&x[node * 16 + qh * 8 + 4];
            acc[0] = u0.x; acc[1] = u0.y; acc[2] = u0.z; acc[3] = u0.w;
            acc[4] = u1.x; acc[5] = u1.y; acc[6] = u1.z; acc[7] = u1.w;
        }
        #pragma unroll
        for (int j = 0; j < 8; ++j) aF[j] = (short)f2bf(acc[j]);
    }

    #pragma unroll
    for (int nt = 0; nt < 4; ++nt) {
        const int cidx = nb + nt * 16 + r;
        bf16x8 bF = *(const bf16x8*)(wbf1 + (size_t)cidx * 32 + q * 8);
        f32x4 acc0 = {0.f, 0.f, 0.f, 0.f};
        acc0 = __builtin_amdgcn_mfma_f32_16x16x32_bf16(aF, bF, acc0, 0, 0, 0);
        float bo = bias[cidx];
        #pragma unroll
        for (int reg = 0; reg < 4; ++reg) {
            int row0 = m0 + q * 4 + reg;
            if (row0 < n)
                hout[(size_t)row0 * 128 + cidx] = f2bf(fmaxf(acc0[reg] + bo, 0.0f));
        }
    }
}

// ---- high-occupancy coalesced mean aggregate ------------------------------
// 32 lanes/node = 2 edge-parity streams x 16 dim-lanes (16B each).
// Streams combined via one shfl_xor(16) pass; sub==0 half stores.
__global__ __launch_bounds__(256) void aggregate128_kernel(
    const bf16_t* __restrict__ h, const int* __restrict__ rowptr,
    const int* __restrict__ col, const float* __restrict__ inv,
    bf16_t* __restrict__ aggb, int N) {
    const int t = threadIdx.x;
    const int node = blockIdx.x * 8 + (t >> 5);
    const int sub = (t >> 4) & 1;            // edge-parity stream
    const int li = t & 15;                   // 8-bf16 (16B) column slot
    if (node >= N) return;
    const int lo = rowptr[node], hi = rowptr[node + 1];
    float acc[8];
    #pragma unroll
    for (int j = 0; j < 8; ++j) acc[j] = 0.0f;
    int e = lo + sub;
    for (; e + 6 < hi; e += 8) {             // 4 edges per iter per stream
        int s0 = col[e], s1 = col[e + 2], s2 = col[e + 4], s3 = col[e + 6];
        uint4 v0 = *(const uint4*)&h[(size_t)s0 * 128 + li * 8];
        uint4 v1 = *(const uint4*)&h[(size_t)s1 * 128 + li * 8];
        uint4 v2 = *(const uint4*)&h[(size_t)s2 * 128 + li * 8];
        uint4 v3 = *(const uint4*)&h[(size_t)s3 * 128 + li * 8];
        acc8(acc, v0);
        acc8(acc, v1);
        acc8(acc, v2);
        acc8(acc, v3);
    }
    for (; e < hi; e += 2) {
        uint4 v0 = *(const uint4*)&h[(size_t)col[e] * 128 + li * 8];
        acc8(acc, v0);
    }
    // combine streams: lane ^ 16 flips sub, keeps li and node
    #pragma unroll
    for (int j = 0; j < 8; ++j) acc[j] += __shfl_xor(acc[j], 16);
    if (sub == 0) {
        const float iv = inv[node];
        uint4 pk;
        pk.x = (uint32)f2bf(acc[0] * iv) | ((uint32)f2bf(acc[1] * iv) << 16);
        pk.y = (uint32)f2bf(acc[2] * iv) | ((uint32)f2bf(acc[3] * iv) << 16);
        pk.z = (uint32)f2bf(acc[4] * iv) | ((uint32)f2bf(acc[5] * iv) << 16);
        pk.w = (uint32)f2bf(acc[6] * iv) | ((uint32)f2bf(acc[7] * iv) << 16);
        *(uint4*)&aggb[(size_t)node * 128 + li * 8] = pk;
    }
}

// ---- layers 2/3: MFMA bf16 GEMM, K=256, LDS-staged weights ----------------
// Block = 128 rows x 64 cols (col half c = bid&1). W half (64x256 bf16 =
// 32KB) staged fragment-major: 16B chunk id = (nt*8+ks)*64 + r*4 + q, so a
// wave's ds_read_b128 at fixed (nt,ks) is a lane-bijective span of 1024B
// -> bank-conflict-free. Each wave: 32 rows (2 M-frags), 64 MFMA, bF
// reused x2. A-frags issued before the barrier to overlap staging.
__global__ __launch_bounds__(256) void layer128_mfma_kernel(
    const bf16_t* __restrict__ aggb, const bf16_t* __restrict__ hin,
    const bf16_t* __restrict__ wbf, const float* __restrict__ bias,
    bf16_t* __restrict__ hout, int n) {
    __shared__ bf16_t w_lds[16384];          // 32KB

    const int t = threadIdx.x;
    const int lane = t & 63;
    const int wave = t >> 6;
    const int r = lane & 15;
    const int q = lane >> 4;
    const int c = blockIdx.x & 1;
    const int rowblk = blockIdx.x >> 1;
    const int nbase = c * 64;
    const int m0w = rowblk * 128 + wave * 32;

    // stage W half, fragment-major (2048 x 16B chunks, 8 per thread)
    #pragma unroll
    for (int i = 0; i < 8; ++i) {
        int ch  = i * 256 + t;
        int q_  = ch & 3;
        int r_  = (ch >> 2) & 15;
        int ks_ = (ch >> 6) & 7;
        int nt_ = ch >> 9;
        const bf16_t* s = wbf + (size_t)(nbase + nt_ * 16 + r_) * 256 + ks_ * 32 + q_ * 8;
        *(uint4*)&w_lds[ch * 8] = *(const uint4*)s;
    }

    // A fragments (global, independent; overlap LDS staging)
    bf16x8 aF[2][8];
    #pragma unroll
    for (int mt = 0; mt < 2; ++mt) {
        int node = m0w + mt * 16 + r;
        if (node >= n) node = n - 1;
        const bf16_t* arow = aggb + (size_t)node * 128;
        const bf16_t* hrow = hin + (size_t)node * 128;
        #pragma unroll
        for (int ks = 0; ks < 4; ++ks)
            aF[mt][ks] = *(const bf16x8*)(arow + ks * 32 + q * 8);
        #pragma unroll
        for (int ks = 0; ks < 4; ++ks)
            aF[mt][4 + ks] = *(const bf16x8*)(hrow + ks * 32 + q * 8);
    }
    __syncthreads();

    #pragma unroll
    for (int nt = 0; nt < 4; ++nt) {
        f32x4 acc0 = {0.f, 0.f, 0.f, 0.f};
        f32x4 acc1 = {0.f, 0.f, 0.f, 0.f};
        #pragma unroll
        for (int ks = 0; ks < 8; ++ks) {
            bf16x8 bF = *(const bf16x8*)&w_lds[(size_t)((nt * 8 + ks) * 64 + r * 4 + q) * 8];
            acc0 = __builtin_amdgcn_mfma_f32_16x16x32_bf16(aF[0][ks], bF, acc0, 0, 0, 0);
            acc1 = __builtin_amdgcn_mfma_f32_16x16x32_bf16(aF[1][ks], bF, acc1, 0, 0, 0);
        }
        const int cidx = nbase + nt * 16 + r;
        const float bo = bias[cidx];
        #pragma unroll
        for (int reg = 0; reg < 4; ++reg) {
            int row0 = m0w + q * 4 + reg;
            if (row0 < n)
                hout[(size_t)row0 * 128 + cidx] = f2bf(fmaxf(acc0[reg] + bo, 0.0f));
            int row1 = m0w + 16 + q * 4 + reg;
            if (row1 < n)
                hout[(size_t)row1 * 128 + cidx] = f2bf(fmaxf(acc1[reg] + bo, 0.0f));
        }
    }
}

// ---- head GEMV: out[node][o] = h3[node] . Wh[o] + bh[o] -------------------
// 4 lanes per node, each owns a K-quarter (64B contiguous -> coalesced);
// 4-lane butterfly combine. Wh (2KB) is L1-resident.
__global__ __launch_bounds__(256) void head_gemv_kernel(
    const bf16_t* __restrict__ h3, const float* __restrict__ Wh,
    const float* __restrict__ bh, float* __restrict__ out, int n) {
    const int t = threadIdx.x;
    const int node = blockIdx.x * 64 + (t >> 2);
    const int kq = t & 3;
    if (node >= n) return;
    const bf16_t* hrow = h3 + (size_t)node * 128 + kq * 32;
    bf16x8 hv[4];
    #pragma unroll
    for (int i = 0; i < 4; ++i) hv[i] = *(const bf16x8*)(hrow + i * 8);
    float p[4];
    #pragma unroll
    for (int o = 0; o < 4; ++o) {
        const float* wr = Wh + o * 128 + kq * 32;
        float a = 0.f;
        #pragma unroll
        for (int i = 0; i < 4; ++i) {
            float4 w0 = *(const float4*)(wr + i * 8);
            float4 w1 = *(const float4*)(wr + i * 8 + 4);
            a = fmaf(bf2f((bf16_t)hv[i][0]), w0.x, a);
            a = fmaf(bf2f((bf16_t)hv[i][1]), w0.y, a);
            a = fmaf(bf2f((bf16_t)hv[i][2]), w0.z, a);
            a = fmaf(bf2f((bf16_t)hv[i][3]), w0.w, a);
            a = fmaf(bf2f((bf16_t)hv[i][4]), w1.x, a);
            a = fmaf(bf2f((bf16_t)hv[i][5]), w1.y, a);
            a = fmaf(bf2f((bf16_t)hv[i][6]), w1.z, a);
            a = fmaf(bf2f((bf16_t)hv[i][7]), w1.w, a);
        }
        p[o] = a;
    }
    #pragma unroll
    for (int o = 0; o < 4; ++o) {
        p[o] += __shfl_xor(p[o], 1);
        p[o] += __shfl_xor(p[o], 2);
    }
    out[(size_t)node * 4 + kq] = p[kq] + bh[kq];
}

extern "C" void kernel_launch(void* const* d_in, const int* in_sizes, int n_in,
                              void* d_out, int out_size, void* d_ws, size_t ws_size,
                              hipStream_t stream) {
    const float* x   = (const float*)d_in[0];
    const int*   ei  = (const int*)d_in[1];
    const float* Wl1 = (const float*)d_in[2];
    const float* Wr1 = (const float*)d_in[3];
    const float* b1  = (const float*)d_in[4];
    const float* Wl2 = (const float*)d_in[5];
    const float* Wr2 = (const float*)d_in[6];
    const float* b2  = (const float*)d_in[7];
    const float* Wl3 = (const float*)d_in[8];
    const float* Wr3 = (const float*)d_in[9];
    const float* b3  = (const float*)d_in[10];
    const float* Wh  = (const float*)d_in[11];
    const float* bh  = (const float*)d_in[12];
    float* out = (float*)d_out;

    const int N = in_sizes[0] / 16;
    const int E = in_sizes[1] / 2;
    const int* src = ei;
    const int* dst = ei + E;

    const int nScanBlocks = (N + SCAN_CHUNK - 1) / SCAN_CHUNK;
    const int nZero = (N + 255) >> 8;

    int* deg       = (int*)d_ws;                       // N
    int* rowptr    = deg + N;                          // N+1 (pad 8)
    int* cursor    = rowptr + (N + 8);                 // N
    int* blocksum  = cursor + N;                       // pad 64
    int* col       = blocksum + 64;                    // E
    float* inv     = (float*)(col + E);                // N
    bf16_t* aggb   = (bf16_t*)(inv + N);               // N*128 bf16
    bf16_t* hA     = aggb + (size_t)N * 128;           // N*128 bf16
    bf16_t* hB     = hA + (size_t)N * 128;             // N*128 bf16
    bf16_t* wbf1   = hB + (size_t)N * 128;             // 128*32 bf16
    bf16_t* wbf2   = wbf1 + 128 * 32;                  // 128*256 bf16
    bf16_t* wbf3   = wbf2 + 128 * 256;                 // 128*256 bf16

    const int B = 256;
    auto blocks = [](long total, int b) { return (int)((total + b - 1) / b); };

    // ---- setup + CSR build (5 dispatches) ----
    prep_kernel<<<nZero + 272, B, 0, stream>>>(deg, N, Wl1, Wr1, wbf1,
                                               Wl2, Wr2, wbf2, Wl3, Wr3, wbf3);
    count_deg_kernel<<<blocks(E, B), B, 0, stream>>>(dst, deg, E);
    scan_partial_kernel<<<nScanBlocks, B, 0, stream>>>(deg, blocksum, N);
    scan_final_kernel<<<nScanBlocks, B, 0, stream>>>(deg, blocksum, rowptr, cursor, inv, N);
    fill_csr_kernel<<<blocks(E, B), B, 0, stream>>>(src, dst, cursor, col, E);

    // ---- layer 1: fused x-gather + MFMA (K=32), writes hA ----
    layer16_fused_kernel<<<blocks(N, 32), B, 0, stream>>>(
        x, rowptr, col, inv, wbf1, b1, hA, N);

    // ---- layer 2: aggregate + staged MFMA GEMM, writes hB ----
    const int gemmGrid = 2 * blocks(N, 128);
    aggregate128_kernel<<<blocks(N, 8), B, 0, stream>>>(hA, rowptr, col, inv, aggb, N);
    layer128_mfma_kernel<<<gemmGrid, B, 0, stream>>>(aggb, hA, wbf2, b2, hB, N);

    // ---- layer 3: aggregate + staged MFMA GEMM, writes hA (h3) ----
    aggregate128_kernel<<<blocks(N, 8), B, 0, stream>>>(hB, rowptr, col, inv, aggb, N);
    layer128_mfma_kernel<<<gemmGrid, B, 0, stream>>>(aggb, hB, wbf3, b3, hA, N);

    // ---- head GEMV ----
    head_gemv_kernel<<<blocks(N, 64), B, 0, stream>>>(hA, Wh, bh, out, N);
}

// Round 6
// 272.958 us; speedup vs baseline: 1.1403x; 1.0287x over previous
//
#include <hip/hip_runtime.h>
#include <hip/hip_bf16.h>

// ---------------------------------------------------------------------------
// GraphSAGE (3x SAGEConv mean + linear head), CSR gather formulation.
// R16 = R15 resubmitted verbatim (R15 never ran: container infra failure).
// R15: dispatch-count pass (11 -> 9) + h3 round-trip elimination.
// Model revision from R14: kernels sum to ~115-130us by micro-arithmetic but
// total is 280us -> ~150us is per-dispatch overhead (~10-15us each; also
// explains R10->R11 -4us and R12->R14 +1-dispatch penalty). Changes:
//   - scan_partial+scan_final fused: each block redundantly reduces the
//     preceding chunks (<=48KB int4 L2 reads) -> no blocksum handoff.
//   - layer3 GEMM + head fused: 128x128-col block via TWO 32KB LDS phases
//     (stage W half -> 4 N-frags + in-register head partials -> barrier ->
//     restage other half). Head closed by 16-lane shfl_xor tree. h3 never
//     written to global (-25.6MB).
//   - weight preconversion buffers deleted: GEMMs convert fp32->bf16 while
//     staging LDS; layer16 converts B-frags inline. prep = deg-zero only.
// R14 lesson kept: GEMM B-operands must come from LDS, never per-MFMA global.
// R9 lesson kept: do NOT fuse the random gather into the GEMM kernel.
// ---------------------------------------------------------------------------

#define SCAN_CHUNK 2048

typedef unsigned short bf16_t;
typedef unsigned int uint32;
typedef __attribute__((ext_vector_type(8))) short bf16x8;   // 8 bf16 = 4 VGPRs
typedef __attribute__((ext_vector_type(4))) float f32x4;

__device__ __forceinline__ bf16_t f2bf(float f) {
    uint32 u = __float_as_uint(f);
    u += 0x7fff + ((u >> 16) & 1);           // round-to-nearest-even
    return (bf16_t)(u >> 16);
}
__device__ __forceinline__ float bf2f(bf16_t b) {
    return __uint_as_float((uint32)b << 16);
}
__device__ __forceinline__ void acc8(float* acc, uint4 v) {
    acc[0] += bf2f((bf16_t)(v.x & 0xffff)); acc[1] += bf2f((bf16_t)(v.x >> 16));
    acc[2] += bf2f((bf16_t)(v.y & 0xffff)); acc[3] += bf2f((bf16_t)(v.y >> 16));
    acc[4] += bf2f((bf16_t)(v.z & 0xffff)); acc[5] += bf2f((bf16_t)(v.z >> 16));
    acc[6] += bf2f((bf16_t)(v.w & 0xffff)); acc[7] += bf2f((bf16_t)(v.w >> 16));
}

// ---- zero degree array ----------------------------------------------------
__global__ __launch_bounds__(256) void zero_deg_kernel(int* __restrict__ deg, int N) {
    int i = blockIdx.x * 256 + threadIdx.x;
    if (i < N) deg[i] = 0;
}

__global__ void count_deg_kernel(const int* __restrict__ dst, int* __restrict__ deg, int E) {
    int e = blockIdx.x * 256 + threadIdx.x;
    if (e < E) atomicAdd(&deg[dst[e]], 1);
}

// ---- fused scan: block offset via redundant reduce of preceding chunks ----
__global__ __launch_bounds__(256) void scan_kernel(
    const int* __restrict__ deg, int* __restrict__ rowptr, int* __restrict__ cursor,
    float* __restrict__ inv, int N) {
    __shared__ int s[256];
    __shared__ int blockoff_s;
    const int t = threadIdx.x;
    const int chunk0 = blockIdx.x * SCAN_CHUNK;
    // phase A: off = sum(deg[0..chunk0)) — redundant per block, <=48KB int4 reads
    int off = 0;
    for (int i = t * 4; i < chunk0; i += 1024) {
        int4 d = *(const int4*)&deg[i];
        off += d.x + d.y + d.z + d.w;
    }
    s[t] = off;
    __syncthreads();
    #pragma unroll
    for (int o = 128; o > 0; o >>= 1) {
        if (t < o) s[t] += s[t + o];
        __syncthreads();
    }
    if (t == 0) blockoff_s = s[0];
    __syncthreads();
    // phase B: local inclusive scan of this chunk (8 elems/thread)
    const int base = chunk0 + t * 8;
    int v[8];
    int sum = 0;
    #pragma unroll
    for (int j = 0; j < 8; ++j) {
        int i = base + j;
        v[j] = (i < N) ? deg[i] : 0;
        sum += v[j];
    }
    s[t] = sum;
    __syncthreads();
    for (int o = 1; o < 256; o <<= 1) {
        int val = (t >= o) ? s[t - o] : 0;
        __syncthreads();
        s[t] += val;
        __syncthreads();
    }
    int run = blockoff_s + ((t == 0) ? 0 : s[t - 1]);
    #pragma unroll
    for (int j = 0; j < 8; ++j) {
        int i = base + j;
        if (i < N) {
            rowptr[i] = run;
            cursor[i] = run;
            inv[i] = 1.0f / (float)max(v[j], 1);
            run += v[j];
        }
    }
    if ((int)blockIdx.x == (int)gridDim.x - 1 && t == 255) rowptr[N] = run;
}

__global__ void fill_csr_kernel(const int* __restrict__ src, const int* __restrict__ dst,
                                int* __restrict__ cursor, int* __restrict__ col, int E) {
    int e = blockIdx.x * 256 + threadIdx.x;
    if (e >= E) return;
    int pos = atomicAdd(&cursor[dst[e]], 1);
    col[pos] = src[e];
}

// ---- layer 1 fused: gather x-mean + MFMA (K=32) --------------------------
// 32-node blocks, one 16-row tile per wave. All 4 q-lanes gather (qh = row
// half, qe = edge parity), shfl_xor(32) combine; self-row overwrite q>=2.
// B-frags converted inline from fp32 Wl1/Wr1 (L2-resident; no prebuffer).
__global__ __launch_bounds__(256) void layer16_fused_kernel(
    const float* __restrict__ x, const int* __restrict__ rowptr,
    const int* __restrict__ col, const float* __restrict__ inv,
    const float* __restrict__ Wl1, const float* __restrict__ Wr1,
    const float* __restrict__ bias, bf16_t* __restrict__ hout, int n) {
    const int t = threadIdx.x;
    const int lane = t & 63;
    const int wave = t >> 6;
    const int r = lane & 15;
    const int q = lane >> 4;
    const int qh = q & 1;
    const int qe = q >> 1;
    const int m0 = blockIdx.x * 32 + (wave >> 1) * 16;
    const int nb = (wave & 1) * 64;

    bf16x8 aF;
    {
        int node = m0 + r;
        if (node >= n) node = n - 1;
        float acc[8];
        #pragma unroll
        for (int j = 0; j < 8; ++j) acc[j] = 0.f;
        const int lo = rowptr[node], hi = rowptr[node + 1];
        int e = lo + qe;
        for (; e + 2 < hi; e += 4) {         // two edges per iter per stream
            int s0 = col[e], s1 = col[e + 2];
            float4 u0 = *(const float4*)&x[s0 * 16 + qh * 8];
            float4 u1 = *(const float4*)&x[s0 * 16 + qh * 8 + 4];
            float4 u2 = *(const float4*)&x[s1 * 16 + qh * 8];
            float4 u3 = *(const float4*)&x[s1 * 16 + qh * 8 + 4];
            acc[0] += u0.x + u2.x; acc[1] += u0.y + u2.y;
            acc[2] += u0.z + u2.z; acc[3] += u0.w + u2.w;
            acc[4] += u1.x + u3.x; acc[5] += u1.y + u3.y;
            acc[6] += u1.z + u3.z; acc[7] += u1.w + u3.w;
        }
        for (; e < hi; e += 2) {
            int s0 = col[e];
            float4 u0 = *(const float4*)&x[s0 * 16 + qh * 8];
            float4 u1 = *(const float4*)&x[s0 * 16 + qh * 8 + 4];
            acc[0] += u0.x; acc[1] += u0.y; acc[2] += u0.z; acc[3] += u0.w;
            acc[4] += u1.x; acc[5] += u1.y; acc[6] += u1.z; acc[7] += u1.w;
        }
        // combine the two edge-parity streams (lane ^ 32 flips qe, keeps r,qh)
        #pragma unroll
        for (int j = 0; j < 8; ++j) acc[j] += __shfl_xor(acc[j], 32);
        if (q < 2) {
            float iv = inv[node];
            #pragma unroll
            for (int j = 0; j < 8; ++j) acc[j] *= iv;
        } else {
            // self-row half qh (K slots 16..31 of the fused K=32 fragment)
            float4 u0 = *(const float4*)&x[node * 16 + qh * 8];
            float4 u1 = *(const float4*)&x[node * 16 + qh * 8 + 4];
            acc[0] = u0.x; acc[1] = u0.y; acc[2] = u0.z; acc[3] = u0.w;
            acc[4] = u1.x; acc[5] = u1.y; acc[6] = u1.z; acc[7] = u1.w;
        }
        #pragma unroll
        for (int j = 0; j < 8; ++j) aF[j] = (short)f2bf(acc[j]);
    }

    #pragma unroll
    for (int nt = 0; nt < 4; ++nt) {
        const int cidx = nb + nt * 16 + r;
        // B-frag: K slots q*8..q*8+7 of concat(Wl1|Wr1) row cidx
        const float* wsrc = (q < 2) ? (Wl1 + cidx * 16 + qh * 8)
                                    : (Wr1 + cidx * 16 + qh * 8);
        float4 w0 = *(const float4*)wsrc;
        float4 w1 = *(const float4*)(wsrc + 4);
        bf16x8 bF;
        bF[0] = (short)f2bf(w0.x); bF[1] = (short)f2bf(w0.y);
        bF[2] = (short)f2bf(w0.z); bF[3] = (short)f2bf(w0.w);
        bF[4] = (short)f2bf(w1.x); bF[5] = (short)f2bf(w1.y);
        bF[6] = (short)f2bf(w1.z); bF[7] = (short)f2bf(w1.w);
        f32x4 acc0 = {0.f, 0.f, 0.f, 0.f};
        acc0 = __builtin_amdgcn_mfma_f32_16x16x32_bf16(aF, bF, acc0, 0, 0, 0);
        float bo = bias[cidx];
        #pragma unroll
        for (int reg = 0; reg < 4; ++reg) {
            int row0 = m0 + q * 4 + reg;
            if (row0 < n)
                hout[(size_t)row0 * 128 + cidx] = f2bf(fmaxf(acc0[reg] + bo, 0.0f));
        }
    }
}

// ---- high-occupancy coalesced mean aggregate ------------------------------
// 32 lanes/node = 2 edge-parity streams x 16 dim-lanes (16B each).
// Streams combined via one shfl_xor(16) pass; sub==0 half stores.
__global__ __launch_bounds__(256) void aggregate128_kernel(
    const bf16_t* __restrict__ h, const int* __restrict__ rowptr,
    const int* __restrict__ col, const float* __restrict__ inv,
    bf16_t* __restrict__ aggb, int N) {
    const int t = threadIdx.x;
    const int node = blockIdx.x * 8 + (t >> 5);
    const int sub = (t >> 4) & 1;            // edge-parity stream
    const int li = t & 15;                   // 8-bf16 (16B) column slot
    if (node >= N) return;
    const int lo = rowptr[node], hi = rowptr[node + 1];
    float acc[8];
    #pragma unroll
    for (int j = 0; j < 8; ++j) acc[j] = 0.0f;
    int e = lo + sub;
    for (; e + 6 < hi; e += 8) {             // 4 edges per iter per stream
        int s0 = col[e], s1 = col[e + 2], s2 = col[e + 4], s3 = col[e + 6];
        uint4 v0 = *(const uint4*)&h[(size_t)s0 * 128 + li * 8];
        uint4 v1 = *(const uint4*)&h[(size_t)s1 * 128 + li * 8];
        uint4 v2 = *(const uint4*)&h[(size_t)s2 * 128 + li * 8];
        uint4 v3 = *(const uint4*)&h[(size_t)s3 * 128 + li * 8];
        acc8(acc, v0);
        acc8(acc, v1);
        acc8(acc, v2);
        acc8(acc, v3);
    }
    for (; e < hi; e += 2) {
        uint4 v0 = *(const uint4*)&h[(size_t)col[e] * 128 + li * 8];
        acc8(acc, v0);
    }
    // combine streams: lane ^ 16 flips sub, keeps li and node
    #pragma unroll
    for (int j = 0; j < 8; ++j) acc[j] += __shfl_xor(acc[j], 16);
    if (sub == 0) {
        const float iv = inv[node];
        uint4 pk;
        pk.x = (uint32)f2bf(acc[0] * iv) | ((uint32)f2bf(acc[1] * iv) << 16);
        pk.y = (uint32)f2bf(acc[2] * iv) | ((uint32)f2bf(acc[3] * iv) << 16);
        pk.z = (uint32)f2bf(acc[4] * iv) | ((uint32)f2bf(acc[5] * iv) << 16);
        pk.w = (uint32)f2bf(acc[6] * iv) | ((uint32)f2bf(acc[7] * iv) << 16);
        *(uint4*)&aggb[(size_t)node * 128 + li * 8] = pk;
    }
}

// ---- layer 2: MFMA bf16 GEMM, K=256, LDS-staged + converted weights -------
// Block = 128 rows x 64 cols (col half c = bid&1). W half staged fragment-
// major with inline fp32->bf16 convert (chunk = (nt*8+ks)*64 + r*4 + q; a
// wave's ds_read_b128 at fixed (nt,ks) is a lane-bijective 1024B span).
__global__ __launch_bounds__(256) void layer128_mfma_kernel(
    const bf16_t* __restrict__ aggb, const bf16_t* __restrict__ hin,
    const float* __restrict__ Wl, const float* __restrict__ Wr,
    const float* __restrict__ bias, bf16_t* __restrict__ hout, int n) {
    __shared__ bf16_t w_lds[16384];          // 32KB

    const int t = threadIdx.x;
    const int lane = t & 63;
    const int wave = t >> 6;
    const int r = lane & 15;
    const int q = lane >> 4;
    const int c = blockIdx.x & 1;
    const int rowblk = blockIdx.x >> 1;
    const int nbase = c * 64;
    const int m0w = rowblk * 128 + wave * 32;

    // stage + convert W half, fragment-major (2048 x 16B chunks, 8/thread)
    #pragma unroll
    for (int i = 0; i < 8; ++i) {
        int ch  = i * 256 + t;
        int q_  = ch & 3;
        int r_  = (ch >> 2) & 15;
        int ks_ = (ch >> 6) & 7;
        int nt_ = ch >> 9;
        int cidx = nbase + nt_ * 16 + r_;
        int k0 = ks_ * 32 + q_ * 8;
        const float* src = (k0 < 128) ? (Wl + cidx * 128 + k0)
                                      : (Wr + cidx * 128 + (k0 - 128));
        float4 a = *(const float4*)src;
        float4 b = *(const float4*)(src + 4);
        uint4 pk;
        pk.x = (uint32)f2bf(a.x) | ((uint32)f2bf(a.y) << 16);
        pk.y = (uint32)f2bf(a.z) | ((uint32)f2bf(a.w) << 16);
        pk.z = (uint32)f2bf(b.x) | ((uint32)f2bf(b.y) << 16);
        pk.w = (uint32)f2bf(b.z) | ((uint32)f2bf(b.w) << 16);
        *(uint4*)&w_lds[ch * 8] = pk;
    }

    // A fragments (global, independent; overlap LDS staging)
    bf16x8 aF[2][8];
    #pragma unroll
    for (int mt = 0; mt < 2; ++mt) {
        int node = m0w + mt * 16 + r;
        if (node >= n) node = n - 1;
        const bf16_t* arow = aggb + (size_t)node * 128;
        const bf16_t* hrow = hin + (size_t)node * 128;
        #pragma unroll
        for (int ks = 0; ks < 4; ++ks)
            aF[mt][ks] = *(const bf16x8*)(arow + ks * 32 + q * 8);
        #pragma unroll
        for (int ks = 0; ks < 4; ++ks)
            aF[mt][4 + ks] = *(const bf16x8*)(hrow + ks * 32 + q * 8);
    }
    __syncthreads();

    #pragma unroll
    for (int nt = 0; nt < 4; ++nt) {
        f32x4 acc0 = {0.f, 0.f, 0.f, 0.f};
        f32x4 acc1 = {0.f, 0.f, 0.f, 0.f};
        #pragma unroll
        for (int ks = 0; ks < 8; ++ks) {
            bf16x8 bF = *(const bf16x8*)&w_lds[(size_t)((nt * 8 + ks) * 64 + r * 4 + q) * 8];
            acc0 = __builtin_amdgcn_mfma_f32_16x16x32_bf16(aF[0][ks], bF, acc0, 0, 0, 0);
            acc1 = __builtin_amdgcn_mfma_f32_16x16x32_bf16(aF[1][ks], bF, acc1, 0, 0, 0);
        }
        const int cidx = nbase + nt * 16 + r;
        const float bo = bias[cidx];
        #pragma unroll
        for (int reg = 0; reg < 4; ++reg) {
            int row0 = m0w + q * 4 + reg;
            if (row0 < n)
                hout[(size_t)row0 * 128 + cidx] = f2bf(fmaxf(acc0[reg] + bo, 0.0f));
            int row1 = m0w + 16 + q * 4 + reg;
            if (row1 < n)
                hout[(size_t)row1 * 128 + cidx] = f2bf(fmaxf(acc1[reg] + bo, 0.0f));
        }
    }
}

// ---- layer 3 GEMM + fused head -------------------------------------------
// Block = 128 rows x ALL 128 cols via two LDS phases (32KB each): stage W
// half c, compute its 4 N-frags, accumulate head partials in-register,
// barrier, restage other half. h3 never hits global. Head dot closed by a
// 16-lane shfl_xor tree; r==0 lanes write out[row][0..3].
__global__ __launch_bounds__(256, 2) void layer128_head_kernel(
    const bf16_t* __restrict__ aggb, const bf16_t* __restrict__ hin,
    const float* __restrict__ Wl, const float* __restrict__ Wr,
    const float* __restrict__ bias, const float* __restrict__ Wh,
    const float* __restrict__ bh, float* __restrict__ out, int n) {
    __shared__ bf16_t w_lds[16384];          // 32KB

    const int t = threadIdx.x;
    const int lane = t & 63;
    const int wave = t >> 6;
    const int r = lane & 15;
    const int q = lane >> 4;
    const int m0w = blockIdx.x * 128 + wave * 32;

    // A fragments for full K=256 (loaded once)
    bf16x8 aF[2][8];
    #pragma unroll
    for (int mt = 0; mt < 2; ++mt) {
        int node = m0w + mt * 16 + r;
        if (node >= n) node = n - 1;
        const bf16_t* arow = aggb + (size_t)node * 128;
        const bf16_t* hrow = hin + (size_t)node * 128;
        #pragma unroll
        for (int ks = 0; ks < 4; ++ks)
            aF[mt][ks] = *(const bf16x8*)(arow + ks * 32 + q * 8);
        #pragma unroll
        for (int ks = 0; ks < 4; ++ks)
            aF[mt][4 + ks] = *(const bf16x8*)(hrow + ks * 32 + q * 8);
    }

    float p[2][4][4];                        // [mt][reg][o] head partials
    #pragma unroll
    for (int mt = 0; mt < 2; ++mt)
        #pragma unroll
        for (int reg = 0; reg < 4; ++reg)
            #pragma unroll
            for (int o = 0; o < 4; ++o) p[mt][reg][o] = 0.f;

    #pragma unroll
    for (int phase = 0; phase < 2; ++phase) {
        if (phase) __syncthreads();          // all reads of phase-0 W done
        const int nbase = phase * 64;
        #pragma unroll
        for (int i = 0; i < 8; ++i) {
            int ch  = i * 256 + t;
            int q_  = ch & 3;
            int r_  = (ch >> 2) & 15;
            int ks_ = (ch >> 6) & 7;
            int nt_ = ch >> 9;
            int cidx = nbase + nt_ * 16 + r_;
            int k0 = ks_ * 32 + q_ * 8;
            const float* src = (k0 < 128) ? (Wl + cidx * 128 + k0)
                                          : (Wr + cidx * 128 + (k0 - 128));
            float4 a = *(const float4*)src;
            float4 b = *(const float4*)(src + 4);
            uint4 pk;
            pk.x = (uint32)f2bf(a.x) | ((uint32)f2bf(a.y) << 16);
            pk.y = (uint32)f2bf(a.z) | ((uint32)f2bf(a.w) << 16);
            pk.z = (uint32)f2bf(b.x) | ((uint32)f2bf(b.y) << 16);
            pk.w = (uint32)f2bf(b.z) | ((uint32)f2bf(b.w) << 16);
            *(uint4*)&w_lds[ch * 8] = pk;
        }
        __syncthreads();

        #pragma unroll
        for (int nt = 0; nt < 4; ++nt) {
            f32x4 acc0 = {0.f, 0.f, 0.f, 0.f};
            f32x4 acc1 = {0.f, 0.f, 0.f, 0.f};
            #pragma unroll
            for (int ks = 0; ks < 8; ++ks) {
                bf16x8 bF = *(const bf16x8*)&w_lds[(size_t)((nt * 8 + ks) * 64 + r * 4 + q) * 8];
                acc0 = __builtin_amdgcn_mfma_f32_16x16x32_bf16(aF[0][ks], bF, acc0, 0, 0, 0);
                acc1 = __builtin_amdgcn_mfma_f32_16x16x32_bf16(aF[1][ks], bF, acc1, 0, 0, 0);
            }
            const int cidx = nbase + nt * 16 + r;
            const float bo = bias[cidx];
            const float wh0 = Wh[cidx], wh1 = Wh[128 + cidx];
            const float wh2 = Wh[256 + cidx], wh3 = Wh[384 + cidx];
            #pragma unroll
            for (int reg = 0; reg < 4; ++reg) {
                float h0 = fmaxf(acc0[reg] + bo, 0.0f);
                float h1 = fmaxf(acc1[reg] + bo, 0.0f);
                p[0][reg][0] += h0 * wh0; p[0][reg][1] += h0 * wh1;
                p[0][reg][2] += h0 * wh2; p[0][reg][3] += h0 * wh3;
                p[1][reg][0] += h1 * wh0; p[1][reg][1] += h1 * wh1;
                p[1][reg][2] += h1 * wh2; p[1][reg][3] += h1 * wh3;
            }
        }
    }

    // close the col-dot: reduce over the 16 r-lanes; r==0 writes 4 outs/row
    #pragma unroll
    for (int mt = 0; mt < 2; ++mt)
        #pragma unroll
        for (int reg = 0; reg < 4; ++reg)
            #pragma unroll
            for (int o = 0; o < 4; ++o) {
                float v = p[mt][reg][o];
                v += __shfl_xor(v, 1);
                v += __shfl_xor(v, 2);
                v += __shfl_xor(v, 4);
                v += __shfl_xor(v, 8);
                if (r == 0) {
                    int row = m0w + mt * 16 + q * 4 + reg;
                    if (row < n) out[(size_t)row * 4 + o] = v + bh[o];
                }
            }
}

extern "C" void kernel_launch(void* const* d_in, const int* in_sizes, int n_in,
                              void* d_out, int out_size, void* d_ws, size_t ws_size,
                              hipStream_t stream) {
    const float* x   = (const float*)d_in[0];
    const int*   ei  = (const int*)d_in[1];
    const float* Wl1 = (const float*)d_in[2];
    const float* Wr1 = (const float*)d_in[3];
    const float* b1  = (const float*)d_in[4];
    const float* Wl2 = (const float*)d_in[5];
    const float* Wr2 = (const float*)d_in[6];
    const float* b2  = (const float*)d_in[7];
    const float* Wl3 = (const float*)d_in[8];
    const float* Wr3 = (const float*)d_in[9];
    const float* b3  = (const float*)d_in[10];
    const float* Wh  = (const float*)d_in[11];
    const float* bh  = (const float*)d_in[12];
    float* out = (float*)d_out;

    const int N = in_sizes[0] / 16;
    const int E = in_sizes[1] / 2;
    const int* src = ei;
    const int* dst = ei + E;

    const int nScanBlocks = (N + SCAN_CHUNK - 1) / SCAN_CHUNK;

    int* deg       = (int*)d_ws;                       // N
    int* rowptr    = deg + N;                          // N+1 (pad 8)
    int* cursor    = rowptr + (N + 8);                 // N
    int* pad       = cursor + N;                       // 64 (alignment keep)
    int* col       = pad + 64;                         // E
    float* inv     = (float*)(col + E);                // N
    bf16_t* aggb   = (bf16_t*)(inv + N);               // N*128 bf16
    bf16_t* hA     = aggb + (size_t)N * 128;           // N*128 bf16
    bf16_t* hB     = hA + (size_t)N * 128;             // N*128 bf16

    const int B = 256;
    auto blocks = [](long total, int b) { return (int)((total + b - 1) / b); };

    // ---- CSR build (4 dispatches) ----
    zero_deg_kernel<<<blocks(N, 256), B, 0, stream>>>(deg, N);
    count_deg_kernel<<<blocks(E, B), B, 0, stream>>>(dst, deg, E);
    scan_kernel<<<nScanBlocks, B, 0, stream>>>(deg, rowptr, cursor, inv, N);
    fill_csr_kernel<<<blocks(E, B), B, 0, stream>>>(src, dst, cursor, col, E);

    // ---- layer 1: fused x-gather + MFMA (K=32), writes hA ----
    layer16_fused_kernel<<<blocks(N, 32), B, 0, stream>>>(
        x, rowptr, col, inv, Wl1, Wr1, b1, hA, N);

    // ---- layer 2: aggregate + staged MFMA GEMM, writes hB ----
    aggregate128_kernel<<<blocks(N, 8), B, 0, stream>>>(hA, rowptr, col, inv, aggb, N);
    layer128_mfma_kernel<<<2 * blocks(N, 128), B, 0, stream>>>(
        aggb, hA, Wl2, Wr2, b2, hB, N);

    // ---- layer 3 GEMM + head fused, writes out directly ----
    aggregate128_kernel<<<blocks(N, 8), B, 0, stream>>>(hB, rowptr, col, inv, aggb, N);
    layer128_head_kernel<<<blocks(N, 128), B, 0, stream>>>(
        aggb, hB, Wl3, Wr3, b3, Wh, bh, out, N);
}